// Round 9
// baseline (403.143 us; speedup 1.0000x reference)
//
#include <hip/hip_runtime.h>
#include <stdint.h>

typedef unsigned short u16;
typedef unsigned long long u64;

#define N_ROWS 32768
#define DIM 256
#define K_CODES 8192
#define TAU 0.3f

// workspace offsets (bytes)
#define A_OFF     0ull            // 32768*256*2 = 16777216
#define B_OFF     16777216ull     // 8192*256*2  = 4194304
#define CN_OFF    20971520ull     // 8192*4
#define PART1_OFF 21004288ull     // 32768*8*4 = 1048576
#define PART2_OFF 22052864ull     // 32768*4*4 = 524288
#define IDX_OFF   22577152ull     // 32768*4
#define HIST_OFF  22708224ull     // 8192*4
#define CNT_OFF   22740992ull     // 16
#define FLAG_OFF  22741008ull     // 32768*4
#define LOSS_OFF  22872080ull     // 8192*4
#define CBT_OFF   23068672ull     // 256*8192*4 = 8388608 (codebook transposed)
#define GMIN2_OFF 31457280ull     // 32768*8 = 262144

// output offsets (float elements)
#define OUT_Q 0
#define OUT_T 8388608
#define OUT_S 8421376

#define BM 128
#define BN 128
#define BK 64
#define JSPLIT 4
#define NT (4 * ((K_CODES / JSPLIT) / BN))   // 64 staged tiles per block
#define RSPLIT 4     // recompute code-split
#define RGRID 512    // persistent recompute grid.x

// packed sentinel: dist=+inf, idx=0xffffffff (any real (dist,idx) sorts below it)
#define PACK_INF ((((u64)0xFF800000u) << 32) | 0xFFFFFFFFull)

typedef _Float16 half8 __attribute__((ext_vector_type(8)));
typedef float floatx4 __attribute__((ext_vector_type(4)));

__device__ __forceinline__ void gload_lds16(const void* g, void* l) {
    __builtin_amdgcn_global_load_lds(
        (const __attribute__((address_space(1))) void*)g,
        (__attribute__((address_space(3))) void*)l,
        16, 0, 0);
}

__device__ __forceinline__ unsigned sortable(float v) {
    unsigned u = __float_as_uint(v);
    return (u & 0x80000000u) ? ~u : (u | 0x80000000u);
}
__device__ __forceinline__ float unsortable(unsigned u) {
    return (u & 0x80000000u) ? __uint_as_float(u & 0x7fffffffu) : __uint_as_float(~u);
}
__device__ __forceinline__ u64 shfl64x(u64 v, int m) {
    return ((u64)(unsigned)__shfl_xor((int)(v >> 32), m, 64) << 32) |
           (unsigned)__shfl_xor((int)(v & 0xffffffffu), m, 64);
}
__device__ __forceinline__ u64 u64min(u64 a, u64 b) { return a < b ? a : b; }
__device__ __forceinline__ u64 u64max(u64 a, u64 b) { return a > b ? a : b; }

// Fused front-end, one dispatch (block-range split):
//   blocks [0,5120)      : fp32 -> f16 cast of inp+cb, fused ||c||^2
//   blocks [5120,5153)   : zero hist + cnt
//   blocks [5153,5665)   : LDS-tiled transpose cbT[d][j] = cb[j][d]
__global__ void prep(const float* __restrict__ inp, const float* __restrict__ cb,
                     u16* __restrict__ A, u16* __restrict__ B, float* __restrict__ cn,
                     unsigned int* __restrict__ hist, int* __restrict__ cnt,
                     float* __restrict__ cbT) {
    __shared__ float tile[64][65];
    const int tid = threadIdx.x;

    if (blockIdx.x >= 5153) {                 // ---- transpose part
        const int bx = blockIdx.x - 5153;
        const int tj = (bx & 127) * 64;       // code-tile base
        const int td = (bx >> 7) * 64;        // dim-tile base
        const int c = (tid & 15) * 4;
        const int r0 = tid >> 4;
#pragma unroll
        for (int p = 0; p < 4; ++p) {
            int r = p * 16 + r0;
            float4 v = *(const float4*)(cb + (size_t)(tj + r) * DIM + td + c);
            tile[r][c] = v.x; tile[r][c + 1] = v.y; tile[r][c + 2] = v.z; tile[r][c + 3] = v.w;
        }
        __syncthreads();
#pragma unroll
        for (int p = 0; p < 4; ++p) {
            int rr = p * 16 + r0;
            float4 w = {tile[c][rr], tile[c + 1][rr], tile[c + 2][rr], tile[c + 3][rr]};
            *(float4*)(cbT + (size_t)(td + rr) * K_CODES + tj + c) = w;
        }
        return;
    }
    if (blockIdx.x >= 5120) {                 // ---- hist/cnt zero part
        int i = (blockIdx.x - 5120) * 256 + tid;
        if (i < K_CODES) hist[i] = 0u;
        else if (i < K_CODES + 4) cnt[i - K_CODES] = 0;
        return;
    }
    // ---- convert part
    int g = blockIdx.x * 256 + tid;           // 40960 rows * 32 threads
    int row = g >> 5;
    int kc = (g & 31) << 3;
    bool isA = row < N_ROWS;
    const float* src = isA ? inp + (size_t)row * DIM + kc
                           : cb + (size_t)(row - N_ROWS) * DIM + kc;
    u16* dst = isA ? A + (size_t)row * DIM + kc
                   : B + (size_t)(row - N_ROWS) * DIM + kc;
    float4 x0 = *(const float4*)(src);
    float4 x1 = *(const float4*)(src + 4);
    float xs[8] = {x0.x, x0.y, x0.z, x0.w, x1.x, x1.y, x1.z, x1.w};
    half8 hv;
    float s = 0.f;
#pragma unroll
    for (int i = 0; i < 8; ++i) {
        hv[i] = (_Float16)xs[i];
        s = fmaf(xs[i], xs[i], s);
    }
    *(half8*)(dst) = hv;
    if (!isA) {
#pragma unroll
        for (int m = 1; m <= 16; m <<= 1) s += __shfl_xor(s, m, 64);
        if ((g & 31) == 0) cn[row - N_ROWS] = s;
    }
}

// stage tile T (jc = T>>2, kk = (T&3)*BK) into buffer BUFI — staging math
// verbatim from the proven R0/R6 kernel (XOR-swizzled source, linear LDS).
#define STAGE_T(T, BUFI)                                                      \
    {                                                                         \
        const int jc_ = (T) >> 2;                                             \
        const int kk_ = ((T) & 3) * BK;                                       \
        const int colBase_ = jBase + jc_ * BN;                                \
        _Pragma("unroll")                                                     \
        for (int it_ = 0; it_ < 4; ++it_) {                                   \
            int r_ = it_ * 32 + str;                                          \
            int cdat_ = sk16 ^ (r_ & 7);                                      \
            int ch_ = it_ * 256 + tid;                                        \
            gload_lds16(A + (size_t)(rowBase + r_) * DIM + kk_ + cdat_ * 8,   \
                        (char*)lsA[BUFI] + ch_ * 16);                         \
            gload_lds16(B + (size_t)(colBase_ + r_) * DIM + kk_ + cdat_ * 8,  \
                        (char*)lsB[BUFI] + ch_ * 16);                         \
        }                                                                     \
    }

// pass 1: the R6-measured best structure (206.5 us): double-buffered staging
// (stage t+1 issued BEFORE compute of t, single vmcnt(0)+barrier per tile),
// full top-2 burst at (t&3)==3 right after the jc tile's final MFMAs, with
// the R5/R7-verified med3 5-op insert.
__launch_bounds__(256, 2)
__global__ void vq_pass1(const u16* __restrict__ A, const u16* __restrict__ B,
                         const float* __restrict__ cn,
                         u64* __restrict__ part1, float* __restrict__ part2) {
    __shared__ __align__(16) _Float16 lsA[2][BM * BK];   // 2 x 16 KiB
    __shared__ __align__(16) _Float16 lsB[2][BN * BK];   // 2 x 16 KiB
    __shared__ u64 t1buf[BM];
    __shared__ float t2buf[BM];

    const int tid = threadIdx.x;
    const int lane = tid & 63;
    const int w = tid >> 6;
    const int wm = w >> 1, wn = w & 1;
    const int l15 = lane & 15;
    const int quad = lane >> 4;
    const int xm = l15 & 7;
    const int rowBase = blockIdx.x * BM;
    const int jBase = blockIdx.y * (K_CODES / JSPLIT);

    float d1[16], d2[16];
    unsigned idxr[16];
#pragma unroll
    for (int i = 0; i < 16; ++i) {
        d1[i] = __builtin_inff(); d2[i] = __builtin_inff(); idxr[i] = 0xffffffffu;
    }

    const int str = tid >> 3;
    const int sk16 = tid & 7;

    // prologue: stage tile 0, drain, barrier
    STAGE_T(0, 0);
    asm volatile("s_waitcnt vmcnt(0)" ::: "memory");
    __builtin_amdgcn_s_barrier();
    asm volatile("" ::: "memory");

    floatx4 acc[4][4];
    int buf = 0;

#pragma unroll 1
    for (int t = 0; t < NT; ++t) {
        // issue next tile's stage into the other buffer (latency hides
        // under this tile's compute)
        if (t + 1 < NT) STAGE_T(t + 1, buf ^ 1);

        if ((t & 3) == 0) {
#pragma unroll
            for (int mi = 0; mi < 4; ++mi)
#pragma unroll
                for (int ni = 0; ni < 4; ++ni)
                    acc[mi][ni] = (floatx4){0.f, 0.f, 0.f, 0.f};
        }

        // compute this tile from lsA[buf]/lsB[buf] — verbatim R0 inner loop
#pragma unroll
        for (int s = 0; s < 2; ++s) {
            const int koff = ((s * 4 + quad) ^ xm) * 8;
            half8 af[4], bf[4];
#pragma unroll
            for (int mi = 0; mi < 4; ++mi)
                af[mi] = *(const half8*)(lsA[buf] + (wm * 64 + mi * 16 + l15) * BK + koff);
#pragma unroll
            for (int ni = 0; ni < 4; ++ni)
                bf[ni] = *(const half8*)(lsB[buf] + (wn * 64 + ni * 16 + l15) * BK + koff);
#pragma unroll
            for (int mi = 0; mi < 4; ++mi)
#pragma unroll
                for (int ni = 0; ni < 4; ++ni)
                    acc[mi][ni] = __builtin_amdgcn_mfma_f32_16x16x32_f16(
                        af[mi], bf[ni], acc[mi][ni], 0, 0, 0);
        }

        // after the 4th k-chunk of a jc tile: top-2 insert burst (runs while
        // next tile's stage is in flight). med3 5-op variant:
        // d1<=d2 invariant => d2' = med3(d1, d2, val).
        if ((t & 3) == 3) {
            const int colBase = jBase + (t >> 2) * BN;
#pragma unroll
            for (int ni = 0; ni < 4; ++ni) {
                unsigned j = (unsigned)(colBase + wn * 64 + ni * 16 + l15);
                float cnj = cn[j];
#pragma unroll
                for (int mi = 0; mi < 4; ++mi) {
#pragma unroll
                    for (int r = 0; r < 4; ++r) {
                        int tr = mi * 4 + r;
                        float val = fmaf(-2.0f, acc[mi][ni][r], cnj);
                        float nd2 = __builtin_amdgcn_fmed3f(d1[tr], d2[tr], val);
                        bool lt = val < d1[tr];
                        d1[tr] = fminf(d1[tr], val);
                        idxr[tr] = lt ? j : idxr[tr];
                        d2[tr] = nd2;
                    }
                }
            }
        }

        asm volatile("s_waitcnt vmcnt(0)" ::: "memory");
        __builtin_amdgcn_s_barrier();
        asm volatile("" ::: "memory");
        buf ^= 1;
    }

    // pack (cold) and merge across the 16 lanes sharing each row — verbatim
    u64 m1[16];
#pragma unroll
    for (int tr = 0; tr < 16; ++tr)
        m1[tr] = ((u64)sortable(d1[tr]) << 32) | idxr[tr];
#pragma unroll
    for (int m = 1; m <= 8; m <<= 1)
#pragma unroll
        for (int tr = 0; tr < 16; ++tr) {
            u64 o1 = shfl64x(m1[tr], m);
            float o2 = __shfl_xor(d2[tr], m, 64);
            u64 n1 = u64min(m1[tr], o1);
            float big = unsortable((unsigned)(u64max(m1[tr], o1) >> 32));
            d2[tr] = fminf(big, fminf(d2[tr], o2));
            m1[tr] = n1;
        }

    // merge the two column-half waves (wn=0 publishes, wn=1 merges & writes)
    if (wn == 0 && l15 == 0) {
#pragma unroll
        for (int tr = 0; tr < 16; ++tr) {
            int rl = wm * 64 + (tr >> 2) * 16 + quad * 4 + (tr & 3);
            t1buf[rl] = m1[tr]; t2buf[rl] = d2[tr];
        }
    }
    __syncthreads();
    if (wn == 1 && l15 == 0) {
#pragma unroll
        for (int tr = 0; tr < 16; ++tr) {
            int rl = wm * 64 + (tr >> 2) * 16 + quad * 4 + (tr & 3);
            u64 o1 = t1buf[rl];
            float o2 = t2buf[rl];
            u64 n1 = u64min(m1[tr], o1);
            float big = unsortable((unsigned)(u64max(m1[tr], o1) >> 32));
            float n2 = fminf(big, fminf(d2[tr], o2));
            size_t p = (size_t)(rowBase + rl) * JSPLIT + blockIdx.y;
            part1[p] = n1;
            part2[p] = n2;
        }
    }
}

// merge JSPLIT partial top-2s; emit idx + flag near-ties for exact recompute.
// Also initializes gmin2[row] = PACK_INF (no memset dispatch).
__global__ void vq_merge(const u64* __restrict__ part1, const float* __restrict__ part2,
                         unsigned* __restrict__ idx32,
                         int* __restrict__ flaglist, int* __restrict__ cnt,
                         u64* __restrict__ gmin2) {
    int row = blockIdx.x * 256 + threadIdx.x;
    u64 m1 = PACK_INF;
    float f2 = __builtin_inff();
#pragma unroll
    for (int y = 0; y < JSPLIT; ++y) {
        u64 p1 = part1[(size_t)row * JSPLIT + y];
        float p2 = part2[(size_t)row * JSPLIT + y];
        u64 n1 = u64min(m1, p1);
        float big = unsortable((unsigned)(u64max(m1, p1) >> 32));
        f2 = fminf(big, fminf(f2, p2));
        m1 = n1;
    }
    gmin2[row] = PACK_INF;
    idx32[row] = (unsigned)(m1 & 0xffffffffu);
    float f1 = unsortable((unsigned)(m1 >> 32));
    if (f2 - f1 < TAU) {
        int p = atomicAdd(cnt, 1);
        flaglist[p] = row;
    }
}

// exact fp32 full-scan argmin for flagged rows — persistent grid (RGRID, RSPLIT):
// each block loops over rowgroups base = bx*8, bx += RGRID. Per iteration:
// 8 rows x 2048 codes (2 MB cbT chunk, L2-resident). Cross-split merge via
// global atomicMin on packed (sortable-dist|idx).
__global__ void vq_recompute(const float* __restrict__ inp, const float* __restrict__ cbT,
                             const float* __restrict__ cn, const int* __restrict__ flaglist,
                             const int* __restrict__ cnt, u64* __restrict__ gmin2) {
    __shared__ float xsT[DIM][8];
    __shared__ u64 wred[8][8];
    const int tid = threadIdx.x;
    const int w = tid >> 6, lane = tid & 63;
    const int n = *cnt;
    const int cbase = blockIdx.y * (K_CODES / RSPLIT) + tid * 4;

#pragma unroll 1
    for (int base = blockIdx.x * 8; base < n; base += RGRID * 8) {
        // stage 8 rows transposed: wave w loads row (base+w), lane covers 4 dims
        {
            int li = base + w;
            int row = flaglist[li < n ? li : (n - 1)];
            float4 a = ((const float4*)(inp + (size_t)row * DIM))[lane];
            int d0 = lane * 4;
            xsT[d0 + 0][w] = a.x; xsT[d0 + 1][w] = a.y;
            xsT[d0 + 2][w] = a.z; xsT[d0 + 3][w] = a.w;
        }
        __syncthreads();

        float4 acc[8];
#pragma unroll
        for (int r = 0; r < 8; ++r) acc[r] = (float4){0.f, 0.f, 0.f, 0.f};

        float4 cv = *(const float4*)(cbT + cbase);      // d = 0
#pragma unroll 4
        for (int d = 0; d < DIM - 1; ++d) {
            float4 nx = *(const float4*)(cbT + (size_t)(d + 1) * K_CODES + cbase);
            float4 xa = *(const float4*)&xsT[d][0];
            float4 xb = *(const float4*)&xsT[d][4];
            float xv[8] = {xa.x, xa.y, xa.z, xa.w, xb.x, xb.y, xb.z, xb.w};
#pragma unroll
            for (int r = 0; r < 8; ++r) {
                acc[r].x = fmaf(xv[r], cv.x, acc[r].x);
                acc[r].y = fmaf(xv[r], cv.y, acc[r].y);
                acc[r].z = fmaf(xv[r], cv.z, acc[r].z);
                acc[r].w = fmaf(xv[r], cv.w, acc[r].w);
            }
            cv = nx;
        }
        {
            const int d = DIM - 1;
            float4 xa = *(const float4*)&xsT[d][0];
            float4 xb = *(const float4*)&xsT[d][4];
            float xv[8] = {xa.x, xa.y, xa.z, xa.w, xb.x, xb.y, xb.z, xb.w};
#pragma unroll
            for (int r = 0; r < 8; ++r) {
                acc[r].x = fmaf(xv[r], cv.x, acc[r].x);
                acc[r].y = fmaf(xv[r], cv.y, acc[r].y);
                acc[r].z = fmaf(xv[r], cv.z, acc[r].z);
                acc[r].w = fmaf(xv[r], cv.w, acc[r].w);
            }
        }

        u64 best[8];
        float4 cn4 = *(const float4*)(cn + cbase);
#pragma unroll
        for (int r = 0; r < 8; ++r) {
            float e0 = cn4.x - 2.0f * acc[r].x;
            float e1 = cn4.y - 2.0f * acc[r].y;
            float e2 = cn4.z - 2.0f * acc[r].z;
            float e3 = cn4.w - 2.0f * acc[r].w;
            u64 b = ((u64)sortable(e0) << 32) | (unsigned)(cbase + 0);
            b = u64min(b, ((u64)sortable(e1) << 32) | (unsigned)(cbase + 1));
            b = u64min(b, ((u64)sortable(e2) << 32) | (unsigned)(cbase + 2));
            b = u64min(b, ((u64)sortable(e3) << 32) | (unsigned)(cbase + 3));
            best[r] = b;
        }

        // reduce across 64 lanes, then across 8 waves, then atomicMin to global
#pragma unroll
        for (int m = 1; m <= 32; m <<= 1)
#pragma unroll
            for (int r = 0; r < 8; ++r) best[r] = u64min(best[r], shfl64x(best[r], m));
        if (lane < 8) wred[w][lane] = best[lane];
        __syncthreads();
        if (tid < 8 && base + tid < n) {
            u64 b = wred[0][tid];
#pragma unroll
            for (int ww = 1; ww < 8; ++ww) b = u64min(b, wred[ww][tid]);
            atomicMin(&gmin2[flaglist[base + tid]], b);
        }
        __syncthreads();   // xsT/wred safe before next iteration's staging
    }
}

// gather codebook rows (resolving recomputed argmins from gmin2 inline),
// write quantized + tokens, per-block loss partial, histogram. idx clamped
// defensively: an invalid index fails absmax instead of faulting the queue.
__global__ void vq_gather(const float* __restrict__ inp, const float* __restrict__ cb,
                          const unsigned* __restrict__ idx32,
                          const u64* __restrict__ gmin2, float* __restrict__ out,
                          float* __restrict__ losspart, unsigned int* __restrict__ hist) {
    __shared__ float red[4];
    int w = threadIdx.x >> 6, lane = threadIdx.x & 63;
    int i = blockIdx.x * 4 + w;
    unsigned idx = idx32[i];
    u64 g = gmin2[i];
    if (g != PACK_INF) idx = (unsigned)(g & 0xffffffffull);
    if (idx >= K_CODES) idx = K_CODES - 1;    // defensive clamp (no-op when valid)
    float4 c = ((const float4*)(cb + (size_t)idx * DIM))[lane];
    float4 x = ((const float4*)(inp + (size_t)i * DIM))[lane];
    ((float4*)(out + OUT_Q))[(size_t)i * 64 + lane] = c;
    float dx = c.x - x.x, dy = c.y - x.y, dz = c.z - x.z, dw = c.w - x.w;
    float s = dx * dx + dy * dy + dz * dz + dw * dw;
#pragma unroll
    for (int m = 32; m; m >>= 1) s += __shfl_xor(s, m, 64);
    if (lane == 0) {
        out[OUT_T + i] = (float)idx;
        red[w] = s;
        atomicAdd(&hist[idx], 1u);
    }
    __syncthreads();
    if (threadIdx.x == 0)
        losspart[blockIdx.x] = red[0] + red[1] + red[2] + red[3];
}

__global__ void vq_finalize(const unsigned int* __restrict__ hist,
                            const float* __restrict__ losspart, float* __restrict__ out) {
    __shared__ float redp[256], redl[256];
    int tid = threadIdx.x;
    float sp = 0.f, sl = 0.f;
    for (int k = tid; k < K_CODES; k += 256) {
        float p = (float)hist[k] * (1.0f / (float)N_ROWS);
        sp += p * logf(p + 1e-10f);
        sl += losspart[k];
    }
    redp[tid] = sp; redl[tid] = sl;
    __syncthreads();
    for (int st = 128; st; st >>= 1) {
        if (tid < st) { redp[tid] += redp[tid + st]; redl[tid] += redl[tid + st]; }
        __syncthreads();
    }
    if (tid == 0) {
        float perp = expf(-redp[0]);
        float e = redl[0] / 8388608.0f;      // mean((q - x)^2)
        out[OUT_S + 0] = 1.25f * e;          // vq_loss
        out[OUT_S + 1] = 0.25f * e;          // commitment_loss
        out[OUT_S + 2] = e;                  // codebook_loss
        out[OUT_S + 3] = perp;               // perplexity
    }
}

extern "C" void kernel_launch(void* const* d_in, const int* in_sizes, int n_in,
                              void* d_out, int out_size, void* d_ws, size_t ws_size,
                              hipStream_t stream) {
    const float* inp = (const float*)d_in[0];
    const float* cb = (const float*)d_in[1];
    float* out = (float*)d_out;
    char* ws = (char*)d_ws;
    u16* A = (u16*)(ws + A_OFF);
    u16* B = (u16*)(ws + B_OFF);
    float* cn = (float*)(ws + CN_OFF);
    u64* part1 = (u64*)(ws + PART1_OFF);
    float* part2 = (float*)(ws + PART2_OFF);
    unsigned* idx32 = (unsigned*)(ws + IDX_OFF);
    unsigned int* hist = (unsigned int*)(ws + HIST_OFF);
    int* cnt = (int*)(ws + CNT_OFF);
    int* flaglist = (int*)(ws + FLAG_OFF);
    float* losspart = (float*)(ws + LOSS_OFF);
    float* cbT = (float*)(ws + CBT_OFF);
    u64* gmin2 = (u64*)(ws + GMIN2_OFF);

    prep<<<5665, 256, 0, stream>>>(inp, cb, A, B, cn, hist, cnt, cbT);
    vq_pass1<<<dim3(N_ROWS / BM, JSPLIT), 256, 0, stream>>>(A, B, cn, part1, part2);
    vq_merge<<<N_ROWS / 256, 256, 0, stream>>>(part1, part2, idx32, flaglist, cnt, gmin2);
    vq_recompute<<<dim3(RGRID, RSPLIT), 512, 0, stream>>>(inp, cbT, cn, flaglist, cnt, gmin2);
    vq_gather<<<N_ROWS / 4, 256, 0, stream>>>(inp, cb, idx32, gmin2, out, losspart, hist);
    vq_finalize<<<1, 256, 0, stream>>>(hist, losspart, out);
}

// Round 10
// 387.443 us; speedup vs baseline: 1.0405x; 1.0405x over previous
//
#include <hip/hip_runtime.h>
#include <stdint.h>

typedef unsigned short u16;
typedef unsigned long long u64;

#define N_ROWS 32768
#define DIM 256
#define K_CODES 8192
#define TAU 0.3f

// workspace offsets (bytes)
#define A_OFF     0ull            // 32768*256*2 = 16777216
#define B_OFF     16777216ull     // 8192*256*2  = 4194304
#define CN_OFF    20971520ull     // 8192*4
#define PART1_OFF 21004288ull     // 32768*8*4 = 1048576
#define PART2_OFF 22052864ull     // 32768*4*4 = 524288
#define IDX_OFF   22577152ull     // 32768*4
#define HIST_OFF  22708224ull     // 8192*4
#define CNT_OFF   22740992ull     // 16
#define FLAG_OFF  22741008ull     // 32768*4
#define LOSS_OFF  22872080ull     // 8192*4
#define CBT_OFF   23068672ull     // 256*8192*4 = 8388608 (codebook transposed)
#define GMIN2_OFF 31457280ull     // 32768*8 = 262144

// output offsets (float elements)
#define OUT_Q 0
#define OUT_T 8388608
#define OUT_S 8421376

#define BM 128
#define BN 128
#define BK 64
#define JSPLIT 4
#define NT (4 * ((K_CODES / JSPLIT) / BN))   // 64 staged tiles per block
#define RSPLIT 4     // recompute code-split
#define RGRID 512    // persistent recompute grid.x

// packed sentinel: dist=+inf, idx=0xffffffff (any real (dist,idx) sorts below it)
#define PACK_INF ((((u64)0xFF800000u) << 32) | 0xFFFFFFFFull)

typedef _Float16 half8 __attribute__((ext_vector_type(8)));
typedef float floatx4 __attribute__((ext_vector_type(4)));

__device__ __forceinline__ void gload_lds16(const void* g, void* l) {
    __builtin_amdgcn_global_load_lds(
        (const __attribute__((address_space(1))) void*)g,
        (__attribute__((address_space(3))) void*)l,
        16, 0, 0);
}

__device__ __forceinline__ unsigned sortable(float v) {
    unsigned u = __float_as_uint(v);
    return (u & 0x80000000u) ? ~u : (u | 0x80000000u);
}
__device__ __forceinline__ float unsortable(unsigned u) {
    return (u & 0x80000000u) ? __uint_as_float(u & 0x7fffffffu) : __uint_as_float(~u);
}
__device__ __forceinline__ u64 shfl64x(u64 v, int m) {
    return ((u64)(unsigned)__shfl_xor((int)(v >> 32), m, 64) << 32) |
           (unsigned)__shfl_xor((int)(v & 0xffffffffu), m, 64);
}
__device__ __forceinline__ u64 u64min(u64 a, u64 b) { return a < b ? a : b; }
__device__ __forceinline__ u64 u64max(u64 a, u64 b) { return a > b ? a : b; }

// Fused front-end, one dispatch (block-range split):
//   blocks [0,5120)      : fp32 -> f16 cast of inp+cb, fused ||c||^2
//   blocks [5120,5153)   : zero hist + cnt
//   blocks [5153,5665)   : LDS-tiled transpose cbT[d][j] = cb[j][d]
__global__ void prep(const float* __restrict__ inp, const float* __restrict__ cb,
                     u16* __restrict__ A, u16* __restrict__ B, float* __restrict__ cn,
                     unsigned int* __restrict__ hist, int* __restrict__ cnt,
                     float* __restrict__ cbT) {
    __shared__ float tile[64][65];
    const int tid = threadIdx.x;

    if (blockIdx.x >= 5153) {                 // ---- transpose part
        const int bx = blockIdx.x - 5153;
        const int tj = (bx & 127) * 64;       // code-tile base
        const int td = (bx >> 7) * 64;        // dim-tile base
        const int c = (tid & 15) * 4;
        const int r0 = tid >> 4;
#pragma unroll
        for (int p = 0; p < 4; ++p) {
            int r = p * 16 + r0;
            float4 v = *(const float4*)(cb + (size_t)(tj + r) * DIM + td + c);
            tile[r][c] = v.x; tile[r][c + 1] = v.y; tile[r][c + 2] = v.z; tile[r][c + 3] = v.w;
        }
        __syncthreads();
#pragma unroll
        for (int p = 0; p < 4; ++p) {
            int rr = p * 16 + r0;
            float4 w = {tile[c][rr], tile[c + 1][rr], tile[c + 2][rr], tile[c + 3][rr]};
            *(float4*)(cbT + (size_t)(td + rr) * K_CODES + tj + c) = w;
        }
        return;
    }
    if (blockIdx.x >= 5120) {                 // ---- hist/cnt zero part
        int i = (blockIdx.x - 5120) * 256 + tid;
        if (i < K_CODES) hist[i] = 0u;
        else if (i < K_CODES + 4) cnt[i - K_CODES] = 0;
        return;
    }
    // ---- convert part
    int g = blockIdx.x * 256 + tid;           // 40960 rows * 32 threads
    int row = g >> 5;
    int kc = (g & 31) << 3;
    bool isA = row < N_ROWS;
    const float* src = isA ? inp + (size_t)row * DIM + kc
                           : cb + (size_t)(row - N_ROWS) * DIM + kc;
    u16* dst = isA ? A + (size_t)row * DIM + kc
                   : B + (size_t)(row - N_ROWS) * DIM + kc;
    float4 x0 = *(const float4*)(src);
    float4 x1 = *(const float4*)(src + 4);
    float xs[8] = {x0.x, x0.y, x0.z, x0.w, x1.x, x1.y, x1.z, x1.w};
    half8 hv;
    float s = 0.f;
#pragma unroll
    for (int i = 0; i < 8; ++i) {
        hv[i] = (_Float16)xs[i];
        s = fmaf(xs[i], xs[i], s);
    }
    *(half8*)(dst) = hv;
    if (!isA) {
#pragma unroll
        for (int m = 1; m <= 16; m <<= 1) s += __shfl_xor(s, m, 64);
        if ((g & 31) == 0) cn[row - N_ROWS] = s;
    }
}

// stage tile T (jc = T>>2, kk = (T&3)*BK) into buffer BUFI — staging math
// verbatim from the proven R0/R6 kernel (XOR-swizzled source, linear LDS).
#define STAGE_T(T, BUFI)                                                      \
    {                                                                         \
        const int jc_ = (T) >> 2;                                             \
        const int kk_ = ((T) & 3) * BK;                                       \
        const int colBase_ = jBase + jc_ * BN;                                \
        _Pragma("unroll")                                                     \
        for (int it_ = 0; it_ < 4; ++it_) {                                   \
            int r_ = it_ * 32 + str;                                          \
            int cdat_ = sk16 ^ (r_ & 7);                                      \
            int ch_ = it_ * 256 + tid;                                        \
            gload_lds16(A + (size_t)(rowBase + r_) * DIM + kk_ + cdat_ * 8,   \
                        (char*)lsA[BUFI] + ch_ * 16);                         \
            gload_lds16(B + (size_t)(colBase_ + r_) * DIM + kk_ + cdat_ * 8,  \
                        (char*)lsB[BUFI] + ch_ * 16);                         \
        }                                                                     \
    }

// pass 1: the R6-measured best structure (206.5 us), VERBATIM — including
// the 6-op ILP-friendly top-2 insert (R9 showed the med3 5-op variant has a
// longer critical path and regressed: 206.5 -> 216, VGPR 96 -> 88).
__launch_bounds__(256, 2)
__global__ void vq_pass1(const u16* __restrict__ A, const u16* __restrict__ B,
                         const float* __restrict__ cn,
                         u64* __restrict__ part1, float* __restrict__ part2) {
    __shared__ __align__(16) _Float16 lsA[2][BM * BK];   // 2 x 16 KiB
    __shared__ __align__(16) _Float16 lsB[2][BN * BK];   // 2 x 16 KiB
    __shared__ u64 t1buf[BM];
    __shared__ float t2buf[BM];

    const int tid = threadIdx.x;
    const int lane = tid & 63;
    const int w = tid >> 6;
    const int wm = w >> 1, wn = w & 1;
    const int l15 = lane & 15;
    const int quad = lane >> 4;
    const int xm = l15 & 7;
    const int rowBase = blockIdx.x * BM;
    const int jBase = blockIdx.y * (K_CODES / JSPLIT);

    float d1[16], d2[16];
    unsigned idxr[16];
#pragma unroll
    for (int i = 0; i < 16; ++i) {
        d1[i] = __builtin_inff(); d2[i] = __builtin_inff(); idxr[i] = 0xffffffffu;
    }

    const int str = tid >> 3;
    const int sk16 = tid & 7;

    // prologue: stage tile 0, drain, barrier
    STAGE_T(0, 0);
    asm volatile("s_waitcnt vmcnt(0)" ::: "memory");
    __builtin_amdgcn_s_barrier();
    asm volatile("" ::: "memory");

    floatx4 acc[4][4];
    int buf = 0;

#pragma unroll 1
    for (int t = 0; t < NT; ++t) {
        // issue next tile's stage into the other buffer (latency hides
        // under this tile's compute)
        if (t + 1 < NT) STAGE_T(t + 1, buf ^ 1);

        if ((t & 3) == 0) {
#pragma unroll
            for (int mi = 0; mi < 4; ++mi)
#pragma unroll
                for (int ni = 0; ni < 4; ++ni)
                    acc[mi][ni] = (floatx4){0.f, 0.f, 0.f, 0.f};
        }

        // compute this tile from lsA[buf]/lsB[buf] — verbatim R0 inner loop
#pragma unroll
        for (int s = 0; s < 2; ++s) {
            const int koff = ((s * 4 + quad) ^ xm) * 8;
            half8 af[4], bf[4];
#pragma unroll
            for (int mi = 0; mi < 4; ++mi)
                af[mi] = *(const half8*)(lsA[buf] + (wm * 64 + mi * 16 + l15) * BK + koff);
#pragma unroll
            for (int ni = 0; ni < 4; ++ni)
                bf[ni] = *(const half8*)(lsB[buf] + (wn * 64 + ni * 16 + l15) * BK + koff);
#pragma unroll
            for (int mi = 0; mi < 4; ++mi)
#pragma unroll
                for (int ni = 0; ni < 4; ++ni)
                    acc[mi][ni] = __builtin_amdgcn_mfma_f32_16x16x32_f16(
                        af[mi], bf[ni], acc[mi][ni], 0, 0, 0);
        }

        // after the 4th k-chunk of a jc tile: top-2 insert burst (runs while
        // next tile's stage is in flight). 6-op ILP form (R6-measured).
        if ((t & 3) == 3) {
            const int colBase = jBase + (t >> 2) * BN;
#pragma unroll
            for (int ni = 0; ni < 4; ++ni) {
                unsigned j = (unsigned)(colBase + wn * 64 + ni * 16 + l15);
                float cnj = cn[j];
#pragma unroll
                for (int mi = 0; mi < 4; ++mi) {
#pragma unroll
                    for (int r = 0; r < 4; ++r) {
                        int tr = mi * 4 + r;
                        float val = fmaf(-2.0f, acc[mi][ni][r], cnj);
                        bool lt = val < d1[tr];
                        float sec = lt ? d1[tr] : val;
                        d2[tr] = fminf(d2[tr], sec);
                        d1[tr] = lt ? val : d1[tr];
                        idxr[tr] = lt ? j : idxr[tr];
                    }
                }
            }
        }

        asm volatile("s_waitcnt vmcnt(0)" ::: "memory");
        __builtin_amdgcn_s_barrier();
        asm volatile("" ::: "memory");
        buf ^= 1;
    }

    // pack (cold) and merge across the 16 lanes sharing each row — verbatim
    u64 m1[16];
#pragma unroll
    for (int tr = 0; tr < 16; ++tr)
        m1[tr] = ((u64)sortable(d1[tr]) << 32) | idxr[tr];
#pragma unroll
    for (int m = 1; m <= 8; m <<= 1)
#pragma unroll
        for (int tr = 0; tr < 16; ++tr) {
            u64 o1 = shfl64x(m1[tr], m);
            float o2 = __shfl_xor(d2[tr], m, 64);
            u64 n1 = u64min(m1[tr], o1);
            float big = unsortable((unsigned)(u64max(m1[tr], o1) >> 32));
            d2[tr] = fminf(big, fminf(d2[tr], o2));
            m1[tr] = n1;
        }

    // merge the two column-half waves (wn=0 publishes, wn=1 merges & writes)
    if (wn == 0 && l15 == 0) {
#pragma unroll
        for (int tr = 0; tr < 16; ++tr) {
            int rl = wm * 64 + (tr >> 2) * 16 + quad * 4 + (tr & 3);
            t1buf[rl] = m1[tr]; t2buf[rl] = d2[tr];
        }
    }
    __syncthreads();
    if (wn == 1 && l15 == 0) {
#pragma unroll
        for (int tr = 0; tr < 16; ++tr) {
            int rl = wm * 64 + (tr >> 2) * 16 + quad * 4 + (tr & 3);
            u64 o1 = t1buf[rl];
            float o2 = t2buf[rl];
            u64 n1 = u64min(m1[tr], o1);
            float big = unsortable((unsigned)(u64max(m1[tr], o1) >> 32));
            float n2 = fminf(big, fminf(d2[tr], o2));
            size_t p = (size_t)(rowBase + rl) * JSPLIT + blockIdx.y;
            part1[p] = n1;
            part2[p] = n2;
        }
    }
}

// merge JSPLIT partial top-2s; emit idx + flag near-ties for exact recompute.
// Also initializes gmin2[row] = PACK_INF (no memset dispatch).
__global__ void vq_merge(const u64* __restrict__ part1, const float* __restrict__ part2,
                         unsigned* __restrict__ idx32,
                         int* __restrict__ flaglist, int* __restrict__ cnt,
                         u64* __restrict__ gmin2) {
    int row = blockIdx.x * 256 + threadIdx.x;
    u64 m1 = PACK_INF;
    float f2 = __builtin_inff();
#pragma unroll
    for (int y = 0; y < JSPLIT; ++y) {
        u64 p1 = part1[(size_t)row * JSPLIT + y];
        float p2 = part2[(size_t)row * JSPLIT + y];
        u64 n1 = u64min(m1, p1);
        float big = unsortable((unsigned)(u64max(m1, p1) >> 32));
        f2 = fminf(big, fminf(f2, p2));
        m1 = n1;
    }
    gmin2[row] = PACK_INF;
    idx32[row] = (unsigned)(m1 & 0xffffffffu);
    float f1 = unsortable((unsigned)(m1 >> 32));
    if (f2 - f1 < TAU) {
        int p = atomicAdd(cnt, 1);
        flaglist[p] = row;
    }
}

// exact fp32 full-scan argmin for flagged rows — persistent grid (RGRID, RSPLIT):
// each block loops over rowgroups base = bx*8, bx += RGRID. Per iteration:
// 8 rows x 2048 codes (2 MB cbT chunk, L2-resident). Cross-split merge via
// global atomicMin on packed (sortable-dist|idx). R7-verbatim (the barrier
// before atomicMin already orders all xsT/wred reuse across iterations).
__global__ void vq_recompute(const float* __restrict__ inp, const float* __restrict__ cbT,
                             const float* __restrict__ cn, const int* __restrict__ flaglist,
                             const int* __restrict__ cnt, u64* __restrict__ gmin2) {
    __shared__ float xsT[DIM][8];
    __shared__ u64 wred[8][8];
    const int tid = threadIdx.x;
    const int w = tid >> 6, lane = tid & 63;
    const int n = *cnt;
    const int cbase = blockIdx.y * (K_CODES / RSPLIT) + tid * 4;

#pragma unroll 1
    for (int base = blockIdx.x * 8; base < n; base += RGRID * 8) {
        // stage 8 rows transposed: wave w loads row (base+w), lane covers 4 dims
        {
            int li = base + w;
            int row = flaglist[li < n ? li : (n - 1)];
            float4 a = ((const float4*)(inp + (size_t)row * DIM))[lane];
            int d0 = lane * 4;
            xsT[d0 + 0][w] = a.x; xsT[d0 + 1][w] = a.y;
            xsT[d0 + 2][w] = a.z; xsT[d0 + 3][w] = a.w;
        }
        __syncthreads();

        float4 acc[8];
#pragma unroll
        for (int r = 0; r < 8; ++r) acc[r] = (float4){0.f, 0.f, 0.f, 0.f};

        float4 cv = *(const float4*)(cbT + cbase);      // d = 0
#pragma unroll 4
        for (int d = 0; d < DIM - 1; ++d) {
            float4 nx = *(const float4*)(cbT + (size_t)(d + 1) * K_CODES + cbase);
            float4 xa = *(const float4*)&xsT[d][0];
            float4 xb = *(const float4*)&xsT[d][4];
            float xv[8] = {xa.x, xa.y, xa.z, xa.w, xb.x, xb.y, xb.z, xb.w};
#pragma unroll
            for (int r = 0; r < 8; ++r) {
                acc[r].x = fmaf(xv[r], cv.x, acc[r].x);
                acc[r].y = fmaf(xv[r], cv.y, acc[r].y);
                acc[r].z = fmaf(xv[r], cv.z, acc[r].z);
                acc[r].w = fmaf(xv[r], cv.w, acc[r].w);
            }
            cv = nx;
        }
        {
            const int d = DIM - 1;
            float4 xa = *(const float4*)&xsT[d][0];
            float4 xb = *(const float4*)&xsT[d][4];
            float xv[8] = {xa.x, xa.y, xa.z, xa.w, xb.x, xb.y, xb.z, xb.w};
#pragma unroll
            for (int r = 0; r < 8; ++r) {
                acc[r].x = fmaf(xv[r], cv.x, acc[r].x);
                acc[r].y = fmaf(xv[r], cv.y, acc[r].y);
                acc[r].z = fmaf(xv[r], cv.z, acc[r].z);
                acc[r].w = fmaf(xv[r], cv.w, acc[r].w);
            }
        }

        u64 best[8];
        float4 cn4 = *(const float4*)(cn + cbase);
#pragma unroll
        for (int r = 0; r < 8; ++r) {
            float e0 = cn4.x - 2.0f * acc[r].x;
            float e1 = cn4.y - 2.0f * acc[r].y;
            float e2 = cn4.z - 2.0f * acc[r].z;
            float e3 = cn4.w - 2.0f * acc[r].w;
            u64 b = ((u64)sortable(e0) << 32) | (unsigned)(cbase + 0);
            b = u64min(b, ((u64)sortable(e1) << 32) | (unsigned)(cbase + 1));
            b = u64min(b, ((u64)sortable(e2) << 32) | (unsigned)(cbase + 2));
            b = u64min(b, ((u64)sortable(e3) << 32) | (unsigned)(cbase + 3));
            best[r] = b;
        }

        // reduce across 64 lanes, then across 8 waves, then atomicMin to global
#pragma unroll
        for (int m = 1; m <= 32; m <<= 1)
#pragma unroll
            for (int r = 0; r < 8; ++r) best[r] = u64min(best[r], shfl64x(best[r], m));
        if (lane < 8) wred[w][lane] = best[lane];
        __syncthreads();
        if (tid < 8 && base + tid < n) {
            u64 b = wred[0][tid];
#pragma unroll
            for (int ww = 1; ww < 8; ++ww) b = u64min(b, wred[ww][tid]);
            atomicMin(&gmin2[flaglist[base + tid]], b);
        }
    }
}

// gather codebook rows (resolving recomputed argmins from gmin2 inline),
// write quantized + tokens, per-block loss partial, histogram. idx clamped
// defensively: an invalid index fails absmax instead of faulting the queue.
__global__ void vq_gather(const float* __restrict__ inp, const float* __restrict__ cb,
                          const unsigned* __restrict__ idx32,
                          const u64* __restrict__ gmin2, float* __restrict__ out,
                          float* __restrict__ losspart, unsigned int* __restrict__ hist) {
    __shared__ float red[4];
    int w = threadIdx.x >> 6, lane = threadIdx.x & 63;
    int i = blockIdx.x * 4 + w;
    unsigned idx = idx32[i];
    u64 g = gmin2[i];
    if (g != PACK_INF) idx = (unsigned)(g & 0xffffffffull);
    if (idx >= K_CODES) idx = K_CODES - 1;    // defensive clamp (no-op when valid)
    float4 c = ((const float4*)(cb + (size_t)idx * DIM))[lane];
    float4 x = ((const float4*)(inp + (size_t)i * DIM))[lane];
    ((float4*)(out + OUT_Q))[(size_t)i * 64 + lane] = c;
    float dx = c.x - x.x, dy = c.y - x.y, dz = c.z - x.z, dw = c.w - x.w;
    float s = dx * dx + dy * dy + dz * dz + dw * dw;
#pragma unroll
    for (int m = 32; m; m >>= 1) s += __shfl_xor(s, m, 64);
    if (lane == 0) {
        out[OUT_T + i] = (float)idx;
        red[w] = s;
        atomicAdd(&hist[idx], 1u);
    }
    __syncthreads();
    if (threadIdx.x == 0)
        losspart[blockIdx.x] = red[0] + red[1] + red[2] + red[3];
}

__global__ void vq_finalize(const unsigned int* __restrict__ hist,
                            const float* __restrict__ losspart, float* __restrict__ out) {
    __shared__ float redp[256], redl[256];
    int tid = threadIdx.x;
    float sp = 0.f, sl = 0.f;
    for (int k = tid; k < K_CODES; k += 256) {
        float p = (float)hist[k] * (1.0f / (float)N_ROWS);
        sp += p * logf(p + 1e-10f);
        sl += losspart[k];
    }
    redp[tid] = sp; redl[tid] = sl;
    __syncthreads();
    for (int st = 128; st; st >>= 1) {
        if (tid < st) { redp[tid] += redp[tid + st]; redl[tid] += redl[tid + st]; }
        __syncthreads();
    }
    if (tid == 0) {
        float perp = expf(-redp[0]);
        float e = redl[0] / 8388608.0f;      // mean((q - x)^2)
        out[OUT_S + 0] = 1.25f * e;          // vq_loss
        out[OUT_S + 1] = 0.25f * e;          // commitment_loss
        out[OUT_S + 2] = e;                  // codebook_loss
        out[OUT_S + 3] = perp;               // perplexity
    }
}

extern "C" void kernel_launch(void* const* d_in, const int* in_sizes, int n_in,
                              void* d_out, int out_size, void* d_ws, size_t ws_size,
                              hipStream_t stream) {
    const float* inp = (const float*)d_in[0];
    const float* cb = (const float*)d_in[1];
    float* out = (float*)d_out;
    char* ws = (char*)d_ws;
    u16* A = (u16*)(ws + A_OFF);
    u16* B = (u16*)(ws + B_OFF);
    float* cn = (float*)(ws + CN_OFF);
    u64* part1 = (u64*)(ws + PART1_OFF);
    float* part2 = (float*)(ws + PART2_OFF);
    unsigned* idx32 = (unsigned*)(ws + IDX_OFF);
    unsigned int* hist = (unsigned int*)(ws + HIST_OFF);
    int* cnt = (int*)(ws + CNT_OFF);
    int* flaglist = (int*)(ws + FLAG_OFF);
    float* losspart = (float*)(ws + LOSS_OFF);
    float* cbT = (float*)(ws + CBT_OFF);
    u64* gmin2 = (u64*)(ws + GMIN2_OFF);

    prep<<<5665, 256, 0, stream>>>(inp, cb, A, B, cn, hist, cnt, cbT);
    vq_pass1<<<dim3(N_ROWS / BM, JSPLIT), 256, 0, stream>>>(A, B, cn, part1, part2);
    vq_merge<<<N_ROWS / 256, 256, 0, stream>>>(part1, part2, idx32, flaglist, cnt, gmin2);
    vq_recompute<<<dim3(RGRID, RSPLIT), 512, 0, stream>>>(inp, cbT, cn, flaglist, cnt, gmin2);
    vq_gather<<<N_ROWS / 4, 256, 0, stream>>>(inp, cb, idx32, gmin2, out, losspart, hist);
    vq_finalize<<<1, 256, 0, stream>>>(hist, losspart, out);
}